// Round 16
// baseline (191.935 us; speedup 1.0000x reference)
//
#include <hip/hip_runtime.h>
#include <stdint.h>

#define SLEN 2048
#define DMODEL 1024
#define NHEADS 16
#define MTOT 8192   // 4 * 2048

typedef short s16x8 __attribute__((ext_vector_type(8)));
typedef short s16x4 __attribute__((ext_vector_type(4)));
typedef float f32x4 __attribute__((ext_vector_type(4)));
typedef float f32x16 __attribute__((ext_vector_type(16)));
typedef unsigned u32x2 __attribute__((ext_vector_type(2)));
typedef unsigned u32x4 __attribute__((ext_vector_type(4)));

static __device__ __forceinline__ unsigned short f2bf(float f) {
  unsigned u = __builtin_bit_cast(unsigned, f);
  u += 0x7fffu + ((u >> 16) & 1u);           // RNE
  return (unsigned short)(u >> 16);
}

static __device__ __forceinline__ unsigned cvt_pk_bf16(float lo, float hi) {
  unsigned r;
  asm("v_cvt_pk_bf16_f32 %0, %1, %2" : "=v"(r) : "v"(lo), "v"(hi));
  return r;
}

static __device__ __forceinline__ void gload_lds16(const void* g, void* l) {
  __builtin_amdgcn_global_load_lds((__attribute__((address_space(1))) void*)g,
                                   (__attribute__((address_space(3))) void*)l,
                                   16, 0, 0);
}

#define MFMA16(a, b, c) __builtin_amdgcn_mfma_f32_16x16x32_bf16(a, b, c, 0, 0, 0)
#define MFMA32(a, b, c) __builtin_amdgcn_mfma_f32_32x32x16_bf16(a, b, c, 0, 0, 0)
// full-rank row swizzle: rows r, r+8, r+16, ... get distinct granule perms
#define SWZ(r) ((((r) & 7) ^ (((r) >> 3) & 7)))

// ---------------- RoPE cos/sin table: [2048][32] each ----------------
__global__ void __launch_bounds__(256) rope_table(const int* __restrict__ pos,
                                                  float* __restrict__ ctab,
                                                  float* __restrict__ stab) {
  int g = blockIdx.x * 256 + threadIdx.x;     // 65536 total
  int s = g >> 5, i = g & 31;
  float p = (float)pos[s];
  float ang = p * exp2f(-(float)i * 0.41524101186092029f);
  ctab[g] = cosf(ang);
  stab[g] = sinf(ang);
}

// ---------------- fp32 -> bf16 convert (x8 vectorized) ----------------
__global__ void __launch_bounds__(256) cvt_f32_bf16(const float* __restrict__ src,
                                                    unsigned short* __restrict__ dst,
                                                    int n8) {
  int i = blockIdx.x * 256 + threadIdx.x;
  if (i >= n8) return;
  f32x4 a = ((const f32x4*)src)[i * 2];
  f32x4 b = ((const f32x4*)src)[i * 2 + 1];
  s16x8 o;
#pragma unroll
  for (int j = 0; j < 4; ++j) o[j] = (short)f2bf(a[j]);
#pragma unroll
  for (int j = 0; j < 4; ++j) o[4 + j] = (short)f2bf(b[j]);
  ((s16x8*)dst)[i] = o;
}

// all four weight matrices in one dispatch (grid.y selects)
__global__ void __launch_bounds__(256) cvt_weights(const float* __restrict__ w0,
                                                   const float* __restrict__ w1,
                                                   const float* __restrict__ w2,
                                                   const float* __restrict__ w3,
                                                   unsigned short* __restrict__ d0,
                                                   unsigned short* __restrict__ d1,
                                                   unsigned short* __restrict__ d2,
                                                   unsigned short* __restrict__ d3) {
  int which = blockIdx.y;
  const float* src = which == 0 ? w0 : which == 1 ? w1 : which == 2 ? w2 : w3;
  unsigned short* dst = which == 0 ? d0 : which == 1 ? d1 : which == 2 ? d2 : d3;
  int i = blockIdx.x * 256 + threadIdx.x;     // 131072 per matrix
  f32x4 a = ((const f32x4*)src)[i * 2];
  f32x4 b = ((const f32x4*)src)[i * 2 + 1];
  s16x8 o;
#pragma unroll
  for (int j = 0; j < 4; ++j) o[j] = (short)f2bf(a[j]);
#pragma unroll
  for (int j = 0; j < 4; ++j) o[4 + j] = (short)f2bf(b[j]);
  ((s16x8*)dst)[i] = o;
}

// ---------------- GEMM: C[M=8192][N] = A[M][K=1024] * B[N][K]^T --------------
// MODE 0: N=1024, store f32 row-major (final Wo projection)
// MODE 3: N=3072 fused QKV against concatenated W_qkv. Per 128-col block:
//         n0>>10 == 0 -> Q (RoPE + scale), 1 -> K (RoPE), 2 -> V^T store.
// XCD mapping: per-XCD working set <= A 2MB + B 2MB = 4MB L2 (n in groups of 8).
// Main loop: 3-buffer 2-deep prefetch with COUNTED vmcnt (never 0 mid-loop)
// + raw s_barrier. (R10: cut QKV 94 -> ~60 us.)
template<int MODE>
__global__ void __launch_bounds__(256) gemm_nt(const unsigned short* __restrict__ A,
                                               const unsigned short* __restrict__ B,
                                               void* __restrict__ dstQ,
                                               void* __restrict__ dstK,
                                               void* __restrict__ dstV,
                                               const float* __restrict__ ctab,
                                               const float* __restrict__ stab,
                                               float scale) {
  __shared__ unsigned short ldsA[3][128 * 32];
  __shared__ unsigned short ldsB[3][128 * 32];
  const int tid = threadIdx.x;
  const int lane = tid & 63;
  const int wave = tid >> 6;
  const int wm = wave >> 1, wn = wave & 1;

  int m0, n0;
  if constexpr (MODE == 3) {
    int flat = blockIdx.y * 24 + blockIdx.x;    // 1536 blocks
    int xcd = flat & 7, idx = flat >> 3;        // idx 0..191 (per-XCD issue order)
    int g = idx >> 6;                           // n-group 0..2 (8 n-blocks each)
    int local = idx & 63;
    int lm = local >> 3, ln = local & 7;
    m0 = (xcd * 8 + lm) * 128;
    n0 = (g * 8 + ln) * 128;
  } else {
    int flat = blockIdx.y * 8 + blockIdx.x;     // 512 blocks
    int logical = (flat & 7) * 64 + (flat >> 3);
    m0 = (logical >> 3) * 128;
    n0 = (logical & 7) * 128;
  }
  const int l15 = lane & 15, lhi = lane >> 4;

  f32x4 acc[4][4] = {};

  auto stage = [&](int buf, int kt) {
    const int kbase = kt * 32;
#pragma unroll
    for (int issue = 0; issue < 2; ++issue) {
      int c = issue * 256 + wave * 64 + lane;   // chunk id 0..511
      int row = c >> 2, kc = c & 3;
      int kcg = kc ^ ((row >> 1) & 3);          // source chunk for this slot
      gload_lds16(A + (size_t)(m0 + row) * 1024 + kbase + kcg * 8,
                  &ldsA[buf][(issue * 256 + wave * 64) * 8]);
      gload_lds16(B + (size_t)(n0 + row) * 1024 + kbase + kcg * 8,
                  &ldsB[buf][(issue * 256 + wave * 64) * 8]);
    }
  };

  // 2-deep prologue: 8 loads/wave in flight
  stage(0, 0);
  stage(1, 1);
  for (int kt = 0; kt < 32; ++kt) {
    if (kt + 1 < 32) {
      asm volatile("s_waitcnt vmcnt(4)" ::: "memory");
    } else {
      asm volatile("s_waitcnt vmcnt(0)" ::: "memory");
    }
    __builtin_amdgcn_s_barrier();
    __builtin_amdgcn_sched_barrier(0);
    if (kt + 2 < 32) stage((kt + 2) % 3, kt + 2);

    const int buf = kt % 3;
    s16x8 af[4], bf[4];
#pragma unroll
    for (int mi = 0; mi < 4; ++mi) {
      int row = wm * 64 + mi * 16 + l15;
      int kc = lhi ^ ((row >> 1) & 3);
      af[mi] = *(const s16x8*)&ldsA[buf][row * 32 + kc * 8];
    }
#pragma unroll
    for (int ni = 0; ni < 4; ++ni) {
      int row = wn * 64 + ni * 16 + l15;
      int kc = lhi ^ ((row >> 1) & 3);
      bf[ni] = *(const s16x8*)&ldsB[buf][row * 32 + kc * 8];
    }
#pragma unroll
    for (int mi = 0; mi < 4; ++mi)
#pragma unroll
      for (int ni = 0; ni < 4; ++ni)
        acc[mi][ni] = MFMA16(af[mi], bf[ni], acc[mi][ni]);
  }

  // C layout: col = lane&15, row = (lane>>4)*4 + i
  if constexpr (MODE == 0) {
    float* dst = (float*)dstQ;
#pragma unroll
    for (int mi = 0; mi < 4; ++mi)
#pragma unroll
      for (int ni = 0; ni < 4; ++ni)
#pragma unroll
        for (int i = 0; i < 4; ++i) {
          int r = m0 + wm * 64 + mi * 16 + lhi * 4 + i;
          int n = n0 + wn * 64 + ni * 16 + l15;
          dst[(size_t)r * 1024 + n] = acc[mi][ni][i];
        }
  } else {  // MODE 3: fused QKV epilogue
    const int which = n0 >> 10;                 // 0=Q 1=K 2=V (uniform per block)
    if (which < 2) {
      unsigned short* dst = (unsigned short*)(which == 0 ? dstQ : dstK);
      const float sc = (which == 0) ? scale : 1.0f;
#pragma unroll
      for (int mi = 0; mi < 4; ++mi)
#pragma unroll
        for (int ni = 0; ni < 4; ++ni)
#pragma unroll
          for (int i = 0; i < 4; ++i) {
            int r = m0 + wm * 64 + mi * 16 + lhi * 4 + i;
            int nn = (n0 & 1023) + wn * 64 + ni * 16 + l15;
            float v = acc[mi][ni][i];
            float p = __shfl_xor(v, 1);         // RoPE partner
            int s = r & (SLEN - 1);
            int d = nn & 63;
            int fi = d >> 1;
            float c = ctab[s * 32 + fi], sn = stab[s * 32 + fi];
            float o = (d & 1) ? (p * sn + v * c) : (v * c - p * sn);
            o *= sc;
            int b = r >> 11, h = nn >> 6;
            dst[((size_t)(b * NHEADS + h) * SLEN + s) * 64 + d] = f2bf(o);
          }
    } else {  // V^T [bh][d][s]
      unsigned short* dst = (unsigned short*)dstV;
#pragma unroll
      for (int mi = 0; mi < 4; ++mi)
#pragma unroll
        for (int ni = 0; ni < 4; ++ni) {
          int r0 = m0 + wm * 64 + mi * 16 + lhi * 4;
          int nn = (n0 & 1023) + wn * 64 + ni * 16 + l15;
          int b = r0 >> 11, s0 = r0 & (SLEN - 1);
          int h = nn >> 6, d = nn & 63;
          s16x4 pk;
#pragma unroll
          for (int i = 0; i < 4; ++i) pk[i] = (short)f2bf(acc[mi][ni][i]);
          *(s16x4*)&dst[((size_t)(b * NHEADS + h) * 64 + d) * SLEN + s0] = pk;
        }
    }
  }
}

// ---------------- causal flash attention, v14: zero-exchange P-pack ---------
// v11/v13 frame (Graeco-Latin map, 1024x256, 4 blocks/CU, proven shfl reduces)
// + PV chunk-k remapping so P never crosses lanes:
//   chunk c, slot (h,j) <-> global k = 16c + 8*(j>>2) + 4h + (j&3).
//   B-side (P): lane (l31,h) natively holds exactly those k's ->
//     pf[c] = {Hv[2c][0], Hv[2c][1], Hv[2c+1][0], Hv[2c+1][1]} — ZERO ops
//     (was 8 shfl_xor + 16 cndmask per tile; permlane attempts in R14/R15
//     failed on unverifiable lane semantics — this needs none).
//   A-side (V): slot j0..3 = k 16c+4h+{0..3}, j4..7 = k 16c+8+4h+{0..3} ->
//     two 8B-contiguous runs: 2x ds_read_b64 (granules 2kc, 2kc+1, +8h bytes).
// Reduces stay __shfl_xor(..,32) (R13-proven) with 4-way partial chains;
// s_setprio(1) around MFMA clusters.
__global__ void __launch_bounds__(256, 4) flash_attn(const unsigned short* __restrict__ Q,
                                                     const unsigned short* __restrict__ K,
                                                     const unsigned short* __restrict__ Vt,
                                                     unsigned short* __restrict__ Obf) {
  __shared__ unsigned short Kbuf[2][64 * 64];   // 8 KB each
  __shared__ unsigned short Vbuf[2][64 * 64];   // rows = d, cols = k-local

  const int tid = threadIdx.x, lane = tid & 63, w = tid >> 6;
  const int l31 = lane & 31, h = lane >> 5;     // h: which 32-lane half

  // XCD round-robin extraction + Graeco-Latin balanced (bh, t)
  int id = blockIdx.x;                          // 0..1023
  int xcd = id & 7, idx = id >> 3;              // idx 0..127 per XCD
  const int s_ = idx & 3;                       // quad slot (consecutive)
  const int bhl = (idx >> 2) & 7;               // local bh
  const int g_ = idx >> 5;                      // stride-32 slot
  const int mul2g = (g_ == 0) ? 0 : (g_ == 1) ? 2 : (g_ == 2) ? 3 : 1;
  const int t = 4 * (s_ ^ g_) + (s_ ^ mul2g);   // 0..15, balanced both ways
  const int bh = xcd * 8 + bhl;
  const int b = bh >> 4, hd = bh & 15;

  const unsigned short* Qb = Q + (size_t)bh * SLEN * 64;
  const unsigned short* Kb = K + (size_t)bh * SLEN * 64;
  const unsigned short* Vb = Vt + (size_t)bh * 64 * SLEN;

  const int qbase = t * 128;
  const int nt = 2 * t + 2;                     // k-tiles incl. diagonal
  const int q_abs = qbase + w * 32 + l31;       // this lane's q column
  const int qminw = qbase + w * 32;             // wave's smallest q

  // stage one 64x64 K tile + one 64x64 Vt tile (16 instrs = 4/wave)
  auto stageKV = [&](int buf, int k0) {
#pragma unroll
    for (int i = 0; i < 2; ++i) {
      int c = i * 256 + tid;                    // 16B chunk 0..511
      int row = c >> 3, cg = c & 7;
      int col = ((cg ^ SWZ(row)) * 8);
      gload_lds16(Kb + (size_t)(k0 + row) * 64 + col, &Kbuf[buf][c * 8]);
      gload_lds16(Vb + (size_t)row * SLEN + k0 + col, &Vbuf[buf][c * 8]);
    }
  };

  // Q B-fragments: lane holds Q[q_abs][dc*16 + h*8 + j]
  s16x8 qf[4];
#pragma unroll
  for (int dc = 0; dc < 4; ++dc)
    qf[dc] = *(const s16x8*)&Qb[(size_t)q_abs * 64 + dc * 16 + h * 8];

  f32x16 accT[2] = {};                          // O^T: d = db*32+(r&3)+8*(r>>2)+4h
  float m_run = -3.0e38f, l_run = 0.f;

  stageKV(0, 0);
  for (int kt = 0; kt < nt; ++kt) {
    const int cur = kt & 1;
    const int k0 = kt * 64;
    if (kt + 1 < nt) {
      stageKV(cur ^ 1, (kt + 1) * 64);
      asm volatile("s_waitcnt vmcnt(4)" ::: "memory");   // stage(kt) landed; (kt+1) in flight
    } else {
      asm volatile("s_waitcnt vmcnt(0)" ::: "memory");
    }
    __builtin_amdgcn_s_barrier();
    __builtin_amdgcn_sched_barrier(0);

    {
      // S^T = K * Q^T : two 32-k blocks
      f32x16 sacc[2] = {};
      __builtin_amdgcn_s_setprio(1);
#pragma unroll
      for (int kb = 0; kb < 2; ++kb) {
#pragma unroll
        for (int dc = 0; dc < 4; ++dc) {
          int r = kb * 32 + l31;
          int g = dc * 2 + h;
          s16x8 kf = *(const s16x8*)&Kbuf[cur][r * 64 + ((g ^ SWZ(r)) * 8)];
          sacc[kb] = MFMA32(kf, qf[dc], sacc[kb]);
        }
      }
      __builtin_amdgcn_s_setprio(0);

      // causal mask on tiles overlapping the wave's q range
      // (k row of element r = (r&3)+8*(r>>2)+4h)
      if (k0 + 63 > qminw) {
#pragma unroll
        for (int kb = 0; kb < 2; ++kb)
#pragma unroll
          for (int r = 0; r < 16; ++r) {
            int k_abs = k0 + kb * 32 + (r & 3) + 8 * (r >> 2) + 4 * h;
            if (k_abs > q_abs) sacc[kb][r] = -3.0e38f;
          }
      }

      // max over 32 own k: 4 independent chains (depth 8), then combine
      float p0 = fmaxf(sacc[0][0], sacc[1][0]);
      float p1 = fmaxf(sacc[0][1], sacc[1][1]);
      float p2 = fmaxf(sacc[0][2], sacc[1][2]);
      float p3 = fmaxf(sacc[0][3], sacc[1][3]);
#pragma unroll
      for (int r = 4; r < 16; r += 4) {
        p0 = fmaxf(p0, fmaxf(sacc[0][r + 0], sacc[1][r + 0]));
        p1 = fmaxf(p1, fmaxf(sacc[0][r + 1], sacc[1][r + 1]));
        p2 = fmaxf(p2, fmaxf(sacc[0][r + 2], sacc[1][r + 2]));
        p3 = fmaxf(p3, fmaxf(sacc[0][r + 3], sacc[1][r + 3]));
      }
      float mx = fmaxf(fmaxf(p0, p1), fmaxf(p2, p3));
      mx = fmaxf(mx, __shfl_xor(mx, 32));       // proven cross-half combine

      if (!__all(mx <= m_run)) {                // defer-rescale
        float mnew = fmaxf(m_run, mx);
        float facv = exp2f(m_run - mnew);
        m_run = mnew;
        l_run *= facv;
#pragma unroll
        for (int db = 0; db < 2; ++db)
#pragma unroll
          for (int r = 0; r < 16; ++r) accT[db][r] *= facv;
      }

      // exp2 + 4-way partial sums + cross-half combine
      float s0 = 0.f, s1 = 0.f, s2 = 0.f, s3 = 0.f;
#pragma unroll
      for (int kb = 0; kb < 2; ++kb)
#pragma unroll
        for (int r = 0; r < 16; r += 4) {
          float e0 = exp2f(sacc[kb][r + 0] - m_run);
          float e1 = exp2f(sacc[kb][r + 1] - m_run);
          float e2 = exp2f(sacc[kb][r + 2] - m_run);
          float e3 = exp2f(sacc[kb][r + 3] - m_run);
          sacc[kb][r + 0] = e0; sacc[kb][r + 1] = e1;
          sacc[kb][r + 2] = e2; sacc[kb][r + 3] = e3;
          s0 += e0; s1 += e1; s2 += e2; s3 += e3;
        }
      float sum = (s0 + s1) + (s2 + s3);
      sum += __shfl_xor(sum, 32);               // proven cross-half combine
      l_run += sum;

      // pack P to bf16: Hv[u][i], u = kb*4+q4 covers k = 8u + 4h + {0..3}
      unsigned Hv[8][2];
#pragma unroll
      for (int kb = 0; kb < 2; ++kb)
#pragma unroll
        for (int q4 = 0; q4 < 4; ++q4) {
          Hv[kb * 4 + q4][0] = cvt_pk_bf16(sacc[kb][q4 * 4 + 0], sacc[kb][q4 * 4 + 1]);
          Hv[kb * 4 + q4][1] = cvt_pk_bf16(sacc[kb][q4 * 4 + 2], sacc[kb][q4 * 4 + 3]);
        }

      // PV with chunk-k remap: slot (h,j) <-> k = 16c + 8*(j>>2) + 4h + (j&3).
      // pf[c] is lane-local (zero exchange); vf = two ds_read_b64 per frag.
      __builtin_amdgcn_s_setprio(1);
#pragma unroll
      for (int db = 0; db < 2; ++db) {
        int r = db * 32 + l31;
        const char* rowp = (const char*)&Vbuf[cur][r * 64];
#pragma unroll
        for (int kc = 0; kc < 4; ++kc) {
          u32x2 vlo = *(const u32x2*)(rowp + (((2 * kc) ^ SWZ(r)) * 16) + 8 * h);
          u32x2 vhi = *(const u32x2*)(rowp + (((2 * kc + 1) ^ SWZ(r)) * 16) + 8 * h);
          u32x4 vv;
          vv[0] = vlo[0]; vv[1] = vlo[1]; vv[2] = vhi[0]; vv[3] = vhi[1];
          u32x4 pv;
          pv[0] = Hv[2 * kc][0]; pv[1] = Hv[2 * kc][1];
          pv[2] = Hv[2 * kc + 1][0]; pv[3] = Hv[2 * kc + 1][1];
          accT[db] = MFMA32(__builtin_bit_cast(s16x8, vv),
                            __builtin_bit_cast(s16x8, pv), accT[db]);
        }
      }
      __builtin_amdgcn_s_setprio(0);
    }

    __builtin_amdgcn_sched_barrier(0);
    __builtin_amdgcn_s_barrier();
  }

  // normalize (lane-local) and store O^T -> [b][s][h*64+d]
  float linv = 1.f / l_run;
#pragma unroll
  for (int db = 0; db < 2; ++db)
#pragma unroll
    for (int q4 = 0; q4 < 4; ++q4) {
      u32x2 pk;
      pk[0] = cvt_pk_bf16(accT[db][q4 * 4 + 0] * linv, accT[db][q4 * 4 + 1] * linv);
      pk[1] = cvt_pk_bf16(accT[db][q4 * 4 + 2] * linv, accT[db][q4 * 4 + 3] * linv);
      int d0 = db * 32 + 8 * q4 + 4 * h;
      *(u32x2*)&Obf[((size_t)(b * SLEN + q_abs)) * DMODEL + hd * 64 + d0] = pk;
    }
}

extern "C" void kernel_launch(void* const* d_in, const int* in_sizes, int n_in,
                              void* d_out, int out_size, void* d_ws, size_t ws_size,
                              hipStream_t stream) {
  const float* x  = (const float*)d_in[0];
  const float* Wq = (const float*)d_in[1];
  const float* Wk = (const float*)d_in[2];
  const float* Wv = (const float*)d_in[3];
  const float* Wo = (const float*)d_in[4];
  const int* pos  = (const int*)d_in[5];
  float* out = (float*)d_out;

  char* ws = (char*)d_ws;
  size_t off = 0;
  auto take = [&](size_t bytes) {
    char* p = ws + off;
    off += (bytes + 255) & ~(size_t)255;
    return p;
  };
  unsigned short* xbf  = (unsigned short*)take((size_t)MTOT * DMODEL * 2);
  unsigned short* wqkv = (unsigned short*)take((size_t)3 * DMODEL * DMODEL * 2);
  unsigned short* wobf = (unsigned short*)take((size_t)DMODEL * DMODEL * 2);
  unsigned short* Qs   = (unsigned short*)take((size_t)64 * SLEN * 64 * 2);
  unsigned short* Ks   = (unsigned short*)take((size_t)64 * SLEN * 64 * 2);
  unsigned short* Vt   = (unsigned short*)take((size_t)64 * 64 * SLEN * 2);
  unsigned short* Obf  = (unsigned short*)take((size_t)MTOT * DMODEL * 2);
  float* ctab = (float*)take((size_t)SLEN * 32 * 4);
  float* stab = (float*)take((size_t)SLEN * 32 * 4);

  rope_table<<<256, 256, 0, stream>>>(pos, ctab, stab);
  cvt_f32_bf16<<<4096, 256, 0, stream>>>(x, xbf, MTOT * DMODEL / 8);
  // Wq, Wk, Wv land contiguously as W_qkv[3072][1024]; Wo separate.
  cvt_weights<<<dim3(512, 4), 256, 0, stream>>>(
      Wq, Wk, Wv, Wo,
      wqkv, wqkv + (size_t)DMODEL * DMODEL, wqkv + (size_t)2 * DMODEL * DMODEL, wobf);

  // fused QKV projection: C[8192][3072], epilogue routes per 128-col block
  gemm_nt<3><<<dim3(24, 64), 256, 0, stream>>>(xbf, wqkv, Qs, Ks, Vt,
                                               ctab, stab, 0.18033688011112042f);

  flash_attn<<<1024, 256, 0, stream>>>(Qs, Ks, Vt, Obf);

  // final projection, fp32 output
  gemm_nt<0><<<dim3(8, 64), 256, 0, stream>>>(Obf, wobf, out, nullptr, nullptr,
                                              nullptr, nullptr, 1.0f);
}

// Round 18
// 178.186 us; speedup vs baseline: 1.0772x; 1.0772x over previous
//
#include <hip/hip_runtime.h>
#include <stdint.h>

#define SLEN 2048
#define DMODEL 1024
#define NHEADS 16
#define MTOT 8192   // 4 * 2048

typedef short s16x8 __attribute__((ext_vector_type(8)));
typedef short s16x4 __attribute__((ext_vector_type(4)));
typedef float f32x4 __attribute__((ext_vector_type(4)));
typedef float f32x16 __attribute__((ext_vector_type(16)));
typedef unsigned u32x2 __attribute__((ext_vector_type(2)));
typedef unsigned u32x4 __attribute__((ext_vector_type(4)));

static __device__ __forceinline__ unsigned short f2bf(float f) {
  unsigned u = __builtin_bit_cast(unsigned, f);
  u += 0x7fffu + ((u >> 16) & 1u);           // RNE
  return (unsigned short)(u >> 16);
}

static __device__ __forceinline__ unsigned cvt_pk_bf16(float lo, float hi) {
  unsigned r;
  asm("v_cvt_pk_bf16_f32 %0, %1, %2" : "=v"(r) : "v"(lo), "v"(hi));
  return r;
}

static __device__ __forceinline__ void gload_lds16(const void* g, void* l) {
  __builtin_amdgcn_global_load_lds((__attribute__((address_space(1))) void*)g,
                                   (__attribute__((address_space(3))) void*)l,
                                   16, 0, 0);
}

// raw v_exp_f32 (libm exp2f routes through __ocml_exp2_f32 with range fixups;
// args here are <=0 finite or -3e38, where v_exp_f32 is exact/correctly 0)
#define EXP2R(x) __builtin_amdgcn_exp2f(x)

#define MFMA16(a, b, c) __builtin_amdgcn_mfma_f32_16x16x32_bf16(a, b, c, 0, 0, 0)
#define MFMA32(a, b, c) __builtin_amdgcn_mfma_f32_32x32x16_bf16(a, b, c, 0, 0, 0)
// full-rank row swizzle: rows r, r+8, r+16, ... get distinct granule perms
#define SWZ(r) ((((r) & 7) ^ (((r) >> 3) & 7)))

// ---------------- RoPE cos/sin table: [2048][32] each ----------------
__global__ void __launch_bounds__(256) rope_table(const int* __restrict__ pos,
                                                  float* __restrict__ ctab,
                                                  float* __restrict__ stab) {
  int g = blockIdx.x * 256 + threadIdx.x;     // 65536 total
  int s = g >> 5, i = g & 31;
  float p = (float)pos[s];
  float ang = p * exp2f(-(float)i * 0.41524101186092029f);
  ctab[g] = cosf(ang);
  stab[g] = sinf(ang);
}

// ---------------- fp32 -> bf16 convert (x8 vectorized) ----------------
__global__ void __launch_bounds__(256) cvt_f32_bf16(const float* __restrict__ src,
                                                    unsigned short* __restrict__ dst,
                                                    int n8) {
  int i = blockIdx.x * 256 + threadIdx.x;
  if (i >= n8) return;
  f32x4 a = ((const f32x4*)src)[i * 2];
  f32x4 b = ((const f32x4*)src)[i * 2 + 1];
  s16x8 o;
#pragma unroll
  for (int j = 0; j < 4; ++j) o[j] = (short)f2bf(a[j]);
#pragma unroll
  for (int j = 0; j < 4; ++j) o[4 + j] = (short)f2bf(b[j]);
  ((s16x8*)dst)[i] = o;
}

// all four weight matrices in one dispatch (grid.y selects)
__global__ void __launch_bounds__(256) cvt_weights(const float* __restrict__ w0,
                                                   const float* __restrict__ w1,
                                                   const float* __restrict__ w2,
                                                   const float* __restrict__ w3,
                                                   unsigned short* __restrict__ d0,
                                                   unsigned short* __restrict__ d1,
                                                   unsigned short* __restrict__ d2,
                                                   unsigned short* __restrict__ d3) {
  int which = blockIdx.y;
  const float* src = which == 0 ? w0 : which == 1 ? w1 : which == 2 ? w2 : w3;
  unsigned short* dst = which == 0 ? d0 : which == 1 ? d1 : which == 2 ? d2 : d3;
  int i = blockIdx.x * 256 + threadIdx.x;     // 131072 per matrix
  f32x4 a = ((const f32x4*)src)[i * 2];
  f32x4 b = ((const f32x4*)src)[i * 2 + 1];
  s16x8 o;
#pragma unroll
  for (int j = 0; j < 4; ++j) o[j] = (short)f2bf(a[j]);
#pragma unroll
  for (int j = 0; j < 4; ++j) o[4 + j] = (short)f2bf(b[j]);
  ((s16x8*)dst)[i] = o;
}

// ---------------- GEMM: C[M=8192][N] = A[M][K=1024] * B[N][K]^T --------------
// MODE 0: N=1024, store f32 row-major (final Wo projection)
// MODE 3: N=3072 fused QKV against concatenated W_qkv. Per 128-col block:
//         n0>>10 == 0 -> Q (RoPE + scale), 1 -> K (RoPE), 2 -> V^T store.
// XCD mapping: per-XCD working set <= A 2MB + B 2MB = 4MB L2 (n in groups of 8).
// Main loop: 3-buffer 2-deep prefetch with COUNTED vmcnt (never 0 mid-loop)
// + raw s_barrier. (R10: cut QKV 94 -> ~60 us.)
template<int MODE>
__global__ void __launch_bounds__(256) gemm_nt(const unsigned short* __restrict__ A,
                                               const unsigned short* __restrict__ B,
                                               void* __restrict__ dstQ,
                                               void* __restrict__ dstK,
                                               void* __restrict__ dstV,
                                               const float* __restrict__ ctab,
                                               const float* __restrict__ stab,
                                               float scale) {
  __shared__ unsigned short ldsA[3][128 * 32];
  __shared__ unsigned short ldsB[3][128 * 32];
  const int tid = threadIdx.x;
  const int lane = tid & 63;
  const int wave = tid >> 6;
  const int wm = wave >> 1, wn = wave & 1;

  int m0, n0;
  if constexpr (MODE == 3) {
    int flat = blockIdx.y * 24 + blockIdx.x;    // 1536 blocks
    int xcd = flat & 7, idx = flat >> 3;        // idx 0..191 (per-XCD issue order)
    int g = idx >> 6;                           // n-group 0..2 (8 n-blocks each)
    int local = idx & 63;
    int lm = local >> 3, ln = local & 7;
    m0 = (xcd * 8 + lm) * 128;
    n0 = (g * 8 + ln) * 128;
  } else {
    int flat = blockIdx.y * 8 + blockIdx.x;     // 512 blocks
    int logical = (flat & 7) * 64 + (flat >> 3);
    m0 = (logical >> 3) * 128;
    n0 = (logical & 7) * 128;
  }
  const int l15 = lane & 15, lhi = lane >> 4;

  f32x4 acc[4][4] = {};

  auto stage = [&](int buf, int kt) {
    const int kbase = kt * 32;
#pragma unroll
    for (int issue = 0; issue < 2; ++issue) {
      int c = issue * 256 + wave * 64 + lane;   // chunk id 0..511
      int row = c >> 2, kc = c & 3;
      int kcg = kc ^ ((row >> 1) & 3);          // source chunk for this slot
      gload_lds16(A + (size_t)(m0 + row) * 1024 + kbase + kcg * 8,
                  &ldsA[buf][(issue * 256 + wave * 64) * 8]);
      gload_lds16(B + (size_t)(n0 + row) * 1024 + kbase + kcg * 8,
                  &ldsB[buf][(issue * 256 + wave * 64) * 8]);
    }
  };

  // 2-deep prologue: 8 loads/wave in flight
  stage(0, 0);
  stage(1, 1);
  for (int kt = 0; kt < 32; ++kt) {
    if (kt + 1 < 32) {
      asm volatile("s_waitcnt vmcnt(4)" ::: "memory");
    } else {
      asm volatile("s_waitcnt vmcnt(0)" ::: "memory");
    }
    __builtin_amdgcn_s_barrier();
    __builtin_amdgcn_sched_barrier(0);
    if (kt + 2 < 32) stage((kt + 2) % 3, kt + 2);

    const int buf = kt % 3;
    s16x8 af[4], bf[4];
#pragma unroll
    for (int mi = 0; mi < 4; ++mi) {
      int row = wm * 64 + mi * 16 + l15;
      int kc = lhi ^ ((row >> 1) & 3);
      af[mi] = *(const s16x8*)&ldsA[buf][row * 32 + kc * 8];
    }
#pragma unroll
    for (int ni = 0; ni < 4; ++ni) {
      int row = wn * 64 + ni * 16 + l15;
      int kc = lhi ^ ((row >> 1) & 3);
      bf[ni] = *(const s16x8*)&ldsB[buf][row * 32 + kc * 8];
    }
#pragma unroll
    for (int mi = 0; mi < 4; ++mi)
#pragma unroll
      for (int ni = 0; ni < 4; ++ni)
        acc[mi][ni] = MFMA16(af[mi], bf[ni], acc[mi][ni]);
  }

  // C layout: col = lane&15, row = (lane>>4)*4 + i
  if constexpr (MODE == 0) {
    float* dst = (float*)dstQ;
#pragma unroll
    for (int mi = 0; mi < 4; ++mi)
#pragma unroll
      for (int ni = 0; ni < 4; ++ni)
#pragma unroll
        for (int i = 0; i < 4; ++i) {
          int r = m0 + wm * 64 + mi * 16 + lhi * 4 + i;
          int n = n0 + wn * 64 + ni * 16 + l15;
          dst[(size_t)r * 1024 + n] = acc[mi][ni][i];
        }
  } else {  // MODE 3: fused QKV epilogue
    const int which = n0 >> 10;                 // 0=Q 1=K 2=V (uniform per block)
    if (which < 2) {
      unsigned short* dst = (unsigned short*)(which == 0 ? dstQ : dstK);
      const float sc = (which == 0) ? scale : 1.0f;
#pragma unroll
      for (int mi = 0; mi < 4; ++mi)
#pragma unroll
        for (int ni = 0; ni < 4; ++ni)
#pragma unroll
          for (int i = 0; i < 4; ++i) {
            int r = m0 + wm * 64 + mi * 16 + lhi * 4 + i;
            int nn = (n0 & 1023) + wn * 64 + ni * 16 + l15;
            float v = acc[mi][ni][i];
            float p = __shfl_xor(v, 1);         // RoPE partner
            int s = r & (SLEN - 1);
            int d = nn & 63;
            int fi = d >> 1;
            float c = ctab[s * 32 + fi], sn = stab[s * 32 + fi];
            float o = (d & 1) ? (p * sn + v * c) : (v * c - p * sn);
            o *= sc;
            int b = r >> 11, h = nn >> 6;
            dst[((size_t)(b * NHEADS + h) * SLEN + s) * 64 + d] = f2bf(o);
          }
    } else {  // V^T [bh][d][s]
      unsigned short* dst = (unsigned short*)dstV;
#pragma unroll
      for (int mi = 0; mi < 4; ++mi)
#pragma unroll
        for (int ni = 0; ni < 4; ++ni) {
          int r0 = m0 + wm * 64 + mi * 16 + lhi * 4;
          int nn = (n0 & 1023) + wn * 64 + ni * 16 + l15;
          int b = r0 >> 11, s0 = r0 & (SLEN - 1);
          int h = nn >> 6, d = nn & 63;
          s16x4 pk;
#pragma unroll
          for (int i = 0; i < 4; ++i) pk[i] = (short)f2bf(acc[mi][ni][i]);
          *(s16x4*)&dst[((size_t)(b * NHEADS + h) * 64 + d) * SLEN + s0] = pk;
        }
    }
  }
}

// ---------------- causal flash attention, v16: stage-after-barrier ----------
// v14 frame (Graeco-Latin map, 1024x256, 4 blocks/CU, zero-exchange P-pack,
// shfl reduces, setprio, raw exp2) with the SINGLE-barrier loop done in the
// SAFE order (R17's race fixed):
//   vmcnt(0)           — wait own stage(kt) loads (the only outstanding ones)
//   s_barrier          — all waves: stage(kt) visible AND compute(kt-1) done
//   stage(kt+1)        — NOW overwriting buf (kt+1)&1 is safe (last read kt-1)
//   compute(kt)        — stage(kt+1) lands under this (~800cy > HBM latency)
// R17 issued stage BEFORE the barrier -> fast wave overwrote a buffer a slow
// wave was still reading in compute(kt-1) (absmax 0.27 race). One barrier per
// tile vs R16's two; same LDS/occupancy.
__global__ void __launch_bounds__(256, 4) flash_attn(const unsigned short* __restrict__ Q,
                                                     const unsigned short* __restrict__ K,
                                                     const unsigned short* __restrict__ Vt,
                                                     unsigned short* __restrict__ Obf) {
  __shared__ unsigned short Kbuf[2][64 * 64];   // 8 KB each
  __shared__ unsigned short Vbuf[2][64 * 64];   // rows = d, cols = k-local

  const int tid = threadIdx.x, lane = tid & 63, w = tid >> 6;
  const int l31 = lane & 31, h = lane >> 5;     // h: which 32-lane half

  // XCD round-robin extraction + Graeco-Latin balanced (bh, t)
  int id = blockIdx.x;                          // 0..1023
  int xcd = id & 7, idx = id >> 3;              // idx 0..127 per XCD
  const int s_ = idx & 3;                       // quad slot (consecutive)
  const int bhl = (idx >> 2) & 7;               // local bh
  const int g_ = idx >> 5;                      // stride-32 slot
  const int mul2g = (g_ == 0) ? 0 : (g_ == 1) ? 2 : (g_ == 2) ? 3 : 1;
  const int t = 4 * (s_ ^ g_) + (s_ ^ mul2g);   // 0..15, balanced both ways
  const int bh = xcd * 8 + bhl;
  const int b = bh >> 4, hd = bh & 15;

  const unsigned short* Qb = Q + (size_t)bh * SLEN * 64;
  const unsigned short* Kb = K + (size_t)bh * SLEN * 64;
  const unsigned short* Vb = Vt + (size_t)bh * 64 * SLEN;

  const int qbase = t * 128;
  const int nt = 2 * t + 2;                     // k-tiles incl. diagonal
  const int q_abs = qbase + w * 32 + l31;       // this lane's q column
  const int qminw = qbase + w * 32;             // wave's smallest q

  // stage one 64x64 K tile + one 64x64 Vt tile (16 instrs = 4/wave)
  auto stageKV = [&](int buf, int k0) {
#pragma unroll
    for (int i = 0; i < 2; ++i) {
      int c = i * 256 + tid;                    // 16B chunk 0..511
      int row = c >> 3, cg = c & 7;
      int col = ((cg ^ SWZ(row)) * 8);
      gload_lds16(Kb + (size_t)(k0 + row) * 64 + col, &Kbuf[buf][c * 8]);
      gload_lds16(Vb + (size_t)row * SLEN + k0 + col, &Vbuf[buf][c * 8]);
    }
  };

  // Q B-fragments: lane holds Q[q_abs][dc*16 + h*8 + j]
  s16x8 qf[4];
#pragma unroll
  for (int dc = 0; dc < 4; ++dc)
    qf[dc] = *(const s16x8*)&Qb[(size_t)q_abs * 64 + dc * 16 + h * 8];

  f32x16 accT[2] = {};                          // O^T: d = db*32+(r&3)+8*(r>>2)+4h
  float m_run = -3.0e38f, l_run = 0.f;

  stageKV(0, 0);
  for (int kt = 0; kt < nt; ++kt) {
    const int cur = kt & 1;
    const int k0 = kt * 64;
    // wait own stage(kt) loads (only outstanding), THEN barrier, THEN prefetch
    asm volatile("s_waitcnt vmcnt(0)" ::: "memory");
    __builtin_amdgcn_s_barrier();
    __builtin_amdgcn_sched_barrier(0);
    if (kt + 1 < nt) stageKV(cur ^ 1, (kt + 1) * 64);

    {
      // S^T = K * Q^T : two 32-k blocks
      f32x16 sacc[2] = {};
      __builtin_amdgcn_s_setprio(1);
#pragma unroll
      for (int kb = 0; kb < 2; ++kb) {
#pragma unroll
        for (int dc = 0; dc < 4; ++dc) {
          int r = kb * 32 + l31;
          int g = dc * 2 + h;
          s16x8 kf = *(const s16x8*)&Kbuf[cur][r * 64 + ((g ^ SWZ(r)) * 8)];
          sacc[kb] = MFMA32(kf, qf[dc], sacc[kb]);
        }
      }
      __builtin_amdgcn_s_setprio(0);

      // causal mask on tiles overlapping the wave's q range
      // (k row of element r = (r&3)+8*(r>>2)+4h)
      if (k0 + 63 > qminw) {
#pragma unroll
        for (int kb = 0; kb < 2; ++kb)
#pragma unroll
          for (int r = 0; r < 16; ++r) {
            int k_abs = k0 + kb * 32 + (r & 3) + 8 * (r >> 2) + 4 * h;
            if (k_abs > q_abs) sacc[kb][r] = -3.0e38f;
          }
      }

      // max over 32 own k: 4 independent chains (depth 8), then combine
      float p0 = fmaxf(sacc[0][0], sacc[1][0]);
      float p1 = fmaxf(sacc[0][1], sacc[1][1]);
      float p2 = fmaxf(sacc[0][2], sacc[1][2]);
      float p3 = fmaxf(sacc[0][3], sacc[1][3]);
#pragma unroll
      for (int r = 4; r < 16; r += 4) {
        p0 = fmaxf(p0, fmaxf(sacc[0][r + 0], sacc[1][r + 0]));
        p1 = fmaxf(p1, fmaxf(sacc[0][r + 1], sacc[1][r + 1]));
        p2 = fmaxf(p2, fmaxf(sacc[0][r + 2], sacc[1][r + 2]));
        p3 = fmaxf(p3, fmaxf(sacc[0][r + 3], sacc[1][r + 3]));
      }
      float mx = fmaxf(fmaxf(p0, p1), fmaxf(p2, p3));
      mx = fmaxf(mx, __shfl_xor(mx, 32));       // proven cross-half combine

      if (!__all(mx <= m_run)) {                // defer-rescale
        float mnew = fmaxf(m_run, mx);
        float facv = EXP2R(m_run - mnew);
        m_run = mnew;
        l_run *= facv;
#pragma unroll
        for (int db = 0; db < 2; ++db)
#pragma unroll
          for (int r = 0; r < 16; ++r) accT[db][r] *= facv;
      }

      // raw-exp2 + 4-way partial sums + cross-half combine
      float s0 = 0.f, s1 = 0.f, s2 = 0.f, s3 = 0.f;
#pragma unroll
      for (int kb = 0; kb < 2; ++kb)
#pragma unroll
        for (int r = 0; r < 16; r += 4) {
          float e0 = EXP2R(sacc[kb][r + 0] - m_run);
          float e1 = EXP2R(sacc[kb][r + 1] - m_run);
          float e2 = EXP2R(sacc[kb][r + 2] - m_run);
          float e3 = EXP2R(sacc[kb][r + 3] - m_run);
          sacc[kb][r + 0] = e0; sacc[kb][r + 1] = e1;
          sacc[kb][r + 2] = e2; sacc[kb][r + 3] = e3;
          s0 += e0; s1 += e1; s2 += e2; s3 += e3;
        }
      float sum = (s0 + s1) + (s2 + s3);
      sum += __shfl_xor(sum, 32);               // proven cross-half combine
      l_run += sum;

      // pack P to bf16: Hv[u][i], u = kb*4+q4 covers k = 8u + 4h + {0..3}
      unsigned Hv[8][2];
#pragma unroll
      for (int kb = 0; kb < 2; ++kb)
#pragma unroll
        for (int q4 = 0; q4 < 4; ++q4) {
          Hv[kb * 4 + q4][0] = cvt_pk_bf16(sacc[kb][q4 * 4 + 0], sacc[kb][q4 * 4 + 1]);
          Hv[kb * 4 + q4][1] = cvt_pk_bf16(sacc[kb][q4 * 4 + 2], sacc[kb][q4 * 4 + 3]);
        }

      // PV with chunk-k remap: slot (h,j) <-> k = 16c + 8*(j>>2) + 4h + (j&3).
      // pf[c] is lane-local (zero exchange); vf = two ds_read_b64 per frag.
      __builtin_amdgcn_s_setprio(1);
#pragma unroll
      for (int db = 0; db < 2; ++db) {
        int r = db * 32 + l31;
        const char* rowp = (const char*)&Vbuf[cur][r * 64];
#pragma unroll
        for (int kc = 0; kc < 4; ++kc) {
          u32x2 vlo = *(const u32x2*)(rowp + (((2 * kc) ^ SWZ(r)) * 16) + 8 * h);
          u32x2 vhi = *(const u32x2*)(rowp + (((2 * kc + 1) ^ SWZ(r)) * 16) + 8 * h);
          u32x4 vv;
          vv[0] = vlo[0]; vv[1] = vlo[1]; vv[2] = vhi[0]; vv[3] = vhi[1];
          u32x4 pv;
          pv[0] = Hv[2 * kc][0]; pv[1] = Hv[2 * kc][1];
          pv[2] = Hv[2 * kc + 1][0]; pv[3] = Hv[2 * kc + 1][1];
          accT[db] = MFMA32(__builtin_bit_cast(s16x8, vv),
                            __builtin_bit_cast(s16x8, pv), accT[db]);
        }
      }
      __builtin_amdgcn_s_setprio(0);
    }
    // no trailing barrier: next iteration's barrier (after vmcnt) provides
    // the compute(kt)-done guarantee before stage(kt+2) overwrites buf cur.
  }

  // normalize (lane-local) and store O^T -> [b][s][h*64+d]
  float linv = 1.f / l_run;
#pragma unroll
  for (int db = 0; db < 2; ++db)
#pragma unroll
    for (int q4 = 0; q4 < 4; ++q4) {
      u32x2 pk;
      pk[0] = cvt_pk_bf16(accT[db][q4 * 4 + 0] * linv, accT[db][q4 * 4 + 1] * linv);
      pk[1] = cvt_pk_bf16(accT[db][q4 * 4 + 2] * linv, accT[db][q4 * 4 + 3] * linv);
      int d0 = db * 32 + 8 * q4 + 4 * h;
      *(u32x2*)&Obf[((size_t)(b * SLEN + q_abs)) * DMODEL + hd * 64 + d0] = pk;
    }
}

extern "C" void kernel_launch(void* const* d_in, const int* in_sizes, int n_in,
                              void* d_out, int out_size, void* d_ws, size_t ws_size,
                              hipStream_t stream) {
  const float* x  = (const float*)d_in[0];
  const float* Wq = (const float*)d_in[1];
  const float* Wk = (const float*)d_in[2];
  const float* Wv = (const float*)d_in[3];
  const float* Wo = (const float*)d_in[4];
  const int* pos  = (const int*)d_in[5];
  float* out = (float*)d_out;

  char* ws = (char*)d_ws;
  size_t off = 0;
  auto take = [&](size_t bytes) {
    char* p = ws + off;
    off += (bytes + 255) & ~(size_t)255;
    return p;
  };
  unsigned short* xbf  = (unsigned short*)take((size_t)MTOT * DMODEL * 2);
  unsigned short* wqkv = (unsigned short*)take((size_t)3 * DMODEL * DMODEL * 2);
  unsigned short* wobf = (unsigned short*)take((size_t)DMODEL * DMODEL * 2);
  unsigned short* Qs   = (unsigned short*)take((size_t)64 * SLEN * 64 * 2);
  unsigned short* Ks   = (unsigned short*)take((size_t)64 * SLEN * 64 * 2);
  unsigned short* Vt   = (unsigned short*)take((size_t)64 * 64 * SLEN * 2);
  unsigned short* Obf  = (unsigned short*)take((size_t)MTOT * DMODEL * 2);
  float* ctab = (float*)take((size_t)SLEN * 32 * 4);
  float* stab = (float*)take((size_t)SLEN * 32 * 4);

  rope_table<<<256, 256, 0, stream>>>(pos, ctab, stab);
  cvt_f32_bf16<<<4096, 256, 0, stream>>>(x, xbf, MTOT * DMODEL / 8);
  // Wq, Wk, Wv land contiguously as W_qkv[3072][1024]; Wo separate.
  cvt_weights<<<dim3(512, 4), 256, 0, stream>>>(
      Wq, Wk, Wv, Wo,
      wqkv, wqkv + (size_t)DMODEL * DMODEL, wqkv + (size_t)2 * DMODEL * DMODEL, wobf);

  // fused QKV projection: C[8192][3072], epilogue routes per 128-col block
  gemm_nt<3><<<dim3(24, 64), 256, 0, stream>>>(xbf, wqkv, Qs, Ks, Vt,
                                               ctab, stab, 0.18033688011112042f);

  flash_attn<<<1024, 256, 0, stream>>>(Qs, Ks, Vt, Obf);

  // final projection, fp32 output
  gemm_nt<0><<<dim3(8, 64), 256, 0, stream>>>(Obf, wobf, out, nullptr, nullptr,
                                              nullptr, nullptr, 1.0f);
}

// Round 19
// 172.418 us; speedup vs baseline: 1.1132x; 1.0335x over previous
//
#include <hip/hip_runtime.h>
#include <stdint.h>

#define SLEN 2048
#define DMODEL 1024
#define NHEADS 16
#define MTOT 8192   // 4 * 2048

typedef short s16x8 __attribute__((ext_vector_type(8)));
typedef short s16x4 __attribute__((ext_vector_type(4)));
typedef float f32x4 __attribute__((ext_vector_type(4)));
typedef float f32x16 __attribute__((ext_vector_type(16)));
typedef unsigned u32x2 __attribute__((ext_vector_type(2)));
typedef unsigned u32x4 __attribute__((ext_vector_type(4)));

static __device__ __forceinline__ unsigned short f2bf(float f) {
  unsigned u = __builtin_bit_cast(unsigned, f);
  u += 0x7fffu + ((u >> 16) & 1u);           // RNE
  return (unsigned short)(u >> 16);
}

static __device__ __forceinline__ unsigned cvt_pk_bf16(float lo, float hi) {
  unsigned r;
  asm("v_cvt_pk_bf16_f32 %0, %1, %2" : "=v"(r) : "v"(lo), "v"(hi));
  return r;
}

static __device__ __forceinline__ void gload_lds16(const void* g, void* l) {
  __builtin_amdgcn_global_load_lds((__attribute__((address_space(1))) void*)g,
                                   (__attribute__((address_space(3))) void*)l,
                                   16, 0, 0);
}

// raw v_exp_f32 (libm exp2f adds range fixups; args <=0 finite or -3e38)
#define EXP2R(x) __builtin_amdgcn_exp2f(x)

#define MFMA16(a, b, c) __builtin_amdgcn_mfma_f32_16x16x32_bf16(a, b, c, 0, 0, 0)
#define MFMA32(a, b, c) __builtin_amdgcn_mfma_f32_32x32x16_bf16(a, b, c, 0, 0, 0)
// full-rank row swizzle: rows r, r+8, r+16, ... get distinct granule perms
#define SWZ(r) ((((r) & 7) ^ (((r) >> 3) & 7)))

// ------------- fused prep: x->bf16, W->bf16, RoPE tables (one dispatch) -----
__global__ void __launch_bounds__(256) prep(const float* __restrict__ x,
                                            const float* __restrict__ Wq,
                                            const float* __restrict__ Wk,
                                            const float* __restrict__ Wv,
                                            const float* __restrict__ Wo,
                                            const int* __restrict__ pos,
                                            unsigned short* __restrict__ xbf,
                                            unsigned short* __restrict__ wqkv,
                                            unsigned short* __restrict__ wobf,
                                            float* __restrict__ ctab,
                                            float* __restrict__ stab) {
  int blk = blockIdx.x;
  if (blk < 4096) {                           // x: 8M floats, 8/thread
    int i = blk * 256 + threadIdx.x;
    f32x4 a = ((const f32x4*)x)[i * 2];
    f32x4 b = ((const f32x4*)x)[i * 2 + 1];
    s16x8 o;
#pragma unroll
    for (int j = 0; j < 4; ++j) o[j] = (short)f2bf(a[j]);
#pragma unroll
    for (int j = 0; j < 4; ++j) o[4 + j] = (short)f2bf(b[j]);
    ((s16x8*)xbf)[i] = o;
  } else if (blk < 6144) {                    // weights: 4 x 1M floats
    int wsel = (blk - 4096) >> 9;             // 512 blocks per matrix
    const float* src = wsel == 0 ? Wq : wsel == 1 ? Wk : wsel == 2 ? Wv : Wo;
    unsigned short* dst = (wsel < 3) ? (wqkv + (size_t)wsel * DMODEL * DMODEL) : wobf;
    int i = ((blk - 4096) & 511) * 256 + threadIdx.x;
    f32x4 a = ((const f32x4*)src)[i * 2];
    f32x4 b = ((const f32x4*)src)[i * 2 + 1];
    s16x8 o;
#pragma unroll
    for (int j = 0; j < 4; ++j) o[j] = (short)f2bf(a[j]);
#pragma unroll
    for (int j = 0; j < 4; ++j) o[4 + j] = (short)f2bf(b[j]);
    ((s16x8*)dst)[i] = o;
  } else {                                    // rope tables: 65536 entries
    int g = (blk - 6144) * 256 + threadIdx.x;
    int s = g >> 5, i = g & 31;
    float p = (float)pos[s];
    float ang = p * exp2f(-(float)i * 0.41524101186092029f);
    ctab[g] = cosf(ang);
    stab[g] = sinf(ang);
  }
}

// ---------------- QKV GEMM: C[8192][3072] = x * W_qkv^T, 256x128 tile -------
// 512 threads = 8 waves (2m x 2n of 64x64 each, wm=wave>>1 in 0..3, wn=wave&1).
// LDS 72KB (3-buffer A 16KB + B 8KB) -> 2 blocks/CU x 8 waves = 4 waves/SIMD
// (128-tile version was 3/SIMD; R18 profile: 55% idle, stall-bound).
// Same 3-buffer 2-deep counted-vmcnt single-barrier loop; stage = 3 loads/wave
// (2 A-chunks + 1 B-chunk, uniform across waves -> vmcnt(3)).
// Epilogue per 128-col block: n0>>10 = 0 -> Q (RoPE+scale), 1 -> K, 2 -> V^T.
__global__ void __launch_bounds__(512) gemm_qkv(const unsigned short* __restrict__ A,
                                                const unsigned short* __restrict__ B,
                                                unsigned short* __restrict__ dstQ,
                                                unsigned short* __restrict__ dstK,
                                                unsigned short* __restrict__ dstV,
                                                const float* __restrict__ ctab,
                                                const float* __restrict__ stab,
                                                float scale) {
  __shared__ unsigned short ldsA[3][256 * 32];  // 48 KB
  __shared__ unsigned short ldsB[3][128 * 32];  // 24 KB
  const int tid = threadIdx.x;
  const int lane = tid & 63;
  const int wave = tid >> 6;                  // 0..7
  const int wm = wave >> 1, wn = wave & 1;

  // XCD mapping: xcd owns m-panels [4*xcd, 4*xcd+4); n iterated in 3 groups
  // of 8 -> per-XCD L2 working set A 2MB + B 2MB.
  int flat = blockIdx.y * 24 + blockIdx.x;    // 768 blocks
  int xcd = flat & 7, idx = flat >> 3;        // idx 0..95
  int g = idx >> 5;                           // n-group 0..2
  int local = idx & 31;
  int lm = local >> 3, ln = local & 7;
  const int m0 = (xcd * 4 + lm) * 256;
  const int n0 = (g * 8 + ln) * 128;
  const int l15 = lane & 15, lhi = lane >> 4;

  f32x4 acc[4][4] = {};

  auto stage = [&](int buf, int kt) {
    const int kbase = kt * 32;
    // A: 1024 chunks of 16B -> 2 per thread
#pragma unroll
    for (int issue = 0; issue < 2; ++issue) {
      int c = issue * 512 + wave * 64 + lane;
      int row = c >> 2, kc = c & 3;
      int kcg = kc ^ ((row >> 1) & 3);
      gload_lds16(A + (size_t)(m0 + row) * 1024 + kbase + kcg * 8,
                  &ldsA[buf][c * 8]);
    }
    // B: 512 chunks -> 1 per thread
    {
      int c = wave * 64 + lane;
      int row = c >> 2, kc = c & 3;
      int kcg = kc ^ ((row >> 1) & 3);
      gload_lds16(B + (size_t)(n0 + row) * 1024 + kbase + kcg * 8,
                  &ldsB[buf][c * 8]);
    }
  };

  // 2-deep prologue: 6 loads/wave in flight
  stage(0, 0);
  stage(1, 1);
  for (int kt = 0; kt < 32; ++kt) {
    if (kt + 1 < 32) {
      asm volatile("s_waitcnt vmcnt(3)" ::: "memory");   // stage(kt) landed
    } else {
      asm volatile("s_waitcnt vmcnt(0)" ::: "memory");
    }
    __builtin_amdgcn_s_barrier();
    __builtin_amdgcn_sched_barrier(0);
    if (kt + 2 < 32) stage((kt + 2) % 3, kt + 2);

    const int buf = kt % 3;
    s16x8 af[4], bf[4];
#pragma unroll
    for (int mi = 0; mi < 4; ++mi) {
      int row = wm * 64 + mi * 16 + l15;
      int kc = lhi ^ ((row >> 1) & 3);
      af[mi] = *(const s16x8*)&ldsA[buf][row * 32 + kc * 8];
    }
#pragma unroll
    for (int ni = 0; ni < 4; ++ni) {
      int row = wn * 64 + ni * 16 + l15;
      int kc = lhi ^ ((row >> 1) & 3);
      bf[ni] = *(const s16x8*)&ldsB[buf][row * 32 + kc * 8];
    }
#pragma unroll
    for (int mi = 0; mi < 4; ++mi)
#pragma unroll
      for (int ni = 0; ni < 4; ++ni)
        acc[mi][ni] = MFMA16(af[mi], bf[ni], acc[mi][ni]);
  }

  // epilogue: C layout col = lane&15, row = (lane>>4)*4 + i
  const int which = n0 >> 10;                 // 0=Q 1=K 2=V (uniform per block)
  if (which < 2) {
    unsigned short* dst = (which == 0) ? dstQ : dstK;
    const float sc = (which == 0) ? scale : 1.0f;
#pragma unroll
    for (int mi = 0; mi < 4; ++mi)
#pragma unroll
      for (int ni = 0; ni < 4; ++ni)
#pragma unroll
        for (int i = 0; i < 4; ++i) {
          int r = m0 + wm * 64 + mi * 16 + lhi * 4 + i;
          int nn = (n0 & 1023) + wn * 64 + ni * 16 + l15;
          float v = acc[mi][ni][i];
          float p = __shfl_xor(v, 1);           // RoPE partner
          int s = r & (SLEN - 1);
          int d = nn & 63;
          int fi = d >> 1;
          float c = ctab[s * 32 + fi], sn = stab[s * 32 + fi];
          float o = (d & 1) ? (p * sn + v * c) : (v * c - p * sn);
          o *= sc;
          int b = r >> 11, h = nn >> 6;
          dst[((size_t)(b * NHEADS + h) * SLEN + s) * 64 + d] = f2bf(o);
        }
  } else {  // V^T [bh][d][s]
#pragma unroll
    for (int mi = 0; mi < 4; ++mi)
#pragma unroll
      for (int ni = 0; ni < 4; ++ni) {
        int r0 = m0 + wm * 64 + mi * 16 + lhi * 4;
        int nn = (n0 & 1023) + wn * 64 + ni * 16 + l15;
        int b = r0 >> 11, s0 = r0 & (SLEN - 1);
        int h = nn >> 6, d = nn & 63;
        s16x4 pk;
#pragma unroll
        for (int i = 0; i < 4; ++i) pk[i] = (short)f2bf(acc[mi][ni][i]);
        *(s16x4*)&dstV[((size_t)(b * NHEADS + h) * 64 + d) * SLEN + s0] = pk;
      }
  }
}

// ---------------- Wo GEMM: out[8192][1024] = Obf * Wo^T (fp32 out) ----------
// Unchanged 128x128 3-buffer structure (R10).
__global__ void __launch_bounds__(256) gemm_wo(const unsigned short* __restrict__ A,
                                               const unsigned short* __restrict__ B,
                                               float* __restrict__ dst) {
  __shared__ unsigned short ldsA[3][128 * 32];
  __shared__ unsigned short ldsB[3][128 * 32];
  const int tid = threadIdx.x;
  const int lane = tid & 63;
  const int wave = tid >> 6;
  const int wm = wave >> 1, wn = wave & 1;

  int flat = blockIdx.y * 8 + blockIdx.x;     // 512 blocks
  int logical = (flat & 7) * 64 + (flat >> 3);
  const int m0 = (logical >> 3) * 128;
  const int n0 = (logical & 7) * 128;
  const int l15 = lane & 15, lhi = lane >> 4;

  f32x4 acc[4][4] = {};

  auto stage = [&](int buf, int kt) {
    const int kbase = kt * 32;
#pragma unroll
    for (int issue = 0; issue < 2; ++issue) {
      int c = issue * 256 + wave * 64 + lane;
      int row = c >> 2, kc = c & 3;
      int kcg = kc ^ ((row >> 1) & 3);
      gload_lds16(A + (size_t)(m0 + row) * 1024 + kbase + kcg * 8,
                  &ldsA[buf][(issue * 256 + wave * 64) * 8]);
      gload_lds16(B + (size_t)(n0 + row) * 1024 + kbase + kcg * 8,
                  &ldsB[buf][(issue * 256 + wave * 64) * 8]);
    }
  };

  stage(0, 0);
  stage(1, 1);
  for (int kt = 0; kt < 32; ++kt) {
    if (kt + 1 < 32) {
      asm volatile("s_waitcnt vmcnt(4)" ::: "memory");
    } else {
      asm volatile("s_waitcnt vmcnt(0)" ::: "memory");
    }
    __builtin_amdgcn_s_barrier();
    __builtin_amdgcn_sched_barrier(0);
    if (kt + 2 < 32) stage((kt + 2) % 3, kt + 2);

    const int buf = kt % 3;
    s16x8 af[4], bf[4];
#pragma unroll
    for (int mi = 0; mi < 4; ++mi) {
      int row = wm * 64 + mi * 16 + l15;
      int kc = lhi ^ ((row >> 1) & 3);
      af[mi] = *(const s16x8*)&ldsA[buf][row * 32 + kc * 8];
    }
#pragma unroll
    for (int ni = 0; ni < 4; ++ni) {
      int row = wn * 64 + ni * 16 + l15;
      int kc = lhi ^ ((row >> 1) & 3);
      bf[ni] = *(const s16x8*)&ldsB[buf][row * 32 + kc * 8];
    }
#pragma unroll
    for (int mi = 0; mi < 4; ++mi)
#pragma unroll
      for (int ni = 0; ni < 4; ++ni)
        acc[mi][ni] = MFMA16(af[mi], bf[ni], acc[mi][ni]);
  }

#pragma unroll
  for (int mi = 0; mi < 4; ++mi)
#pragma unroll
    for (int ni = 0; ni < 4; ++ni)
#pragma unroll
      for (int i = 0; i < 4; ++i) {
        int r = m0 + wm * 64 + mi * 16 + lhi * 4 + i;
        int n = n0 + wn * 64 + ni * 16 + l15;
        dst[(size_t)r * 1024 + n] = acc[mi][ni][i];
      }
}

// ---------------- causal flash attention, v16 (R18, passing) ----------------
__global__ void __launch_bounds__(256, 4) flash_attn(const unsigned short* __restrict__ Q,
                                                     const unsigned short* __restrict__ K,
                                                     const unsigned short* __restrict__ Vt,
                                                     unsigned short* __restrict__ Obf) {
  __shared__ unsigned short Kbuf[2][64 * 64];   // 8 KB each
  __shared__ unsigned short Vbuf[2][64 * 64];   // rows = d, cols = k-local

  const int tid = threadIdx.x, lane = tid & 63, w = tid >> 6;
  const int l31 = lane & 31, h = lane >> 5;     // h: which 32-lane half

  // XCD round-robin extraction + Graeco-Latin balanced (bh, t)
  int id = blockIdx.x;                          // 0..1023
  int xcd = id & 7, idx = id >> 3;              // idx 0..127 per XCD
  const int s_ = idx & 3;
  const int bhl = (idx >> 2) & 7;
  const int g_ = idx >> 5;
  const int mul2g = (g_ == 0) ? 0 : (g_ == 1) ? 2 : (g_ == 2) ? 3 : 1;
  const int t = 4 * (s_ ^ g_) + (s_ ^ mul2g);   // 0..15, balanced both ways
  const int bh = xcd * 8 + bhl;
  const int b = bh >> 4, hd = bh & 15;

  const unsigned short* Qb = Q + (size_t)bh * SLEN * 64;
  const unsigned short* Kb = K + (size_t)bh * SLEN * 64;
  const unsigned short* Vb = Vt + (size_t)bh * 64 * SLEN;

  const int qbase = t * 128;
  const int nt = 2 * t + 2;                     // k-tiles incl. diagonal
  const int q_abs = qbase + w * 32 + l31;
  const int qminw = qbase + w * 32;

  auto stageKV = [&](int buf, int k0) {
#pragma unroll
    for (int i = 0; i < 2; ++i) {
      int c = i * 256 + tid;                    // 16B chunk 0..511
      int row = c >> 3, cg = c & 7;
      int col = ((cg ^ SWZ(row)) * 8);
      gload_lds16(Kb + (size_t)(k0 + row) * 64 + col, &Kbuf[buf][c * 8]);
      gload_lds16(Vb + (size_t)row * SLEN + k0 + col, &Vbuf[buf][c * 8]);
    }
  };

  s16x8 qf[4];
#pragma unroll
  for (int dc = 0; dc < 4; ++dc)
    qf[dc] = *(const s16x8*)&Qb[(size_t)q_abs * 64 + dc * 16 + h * 8];

  f32x16 accT[2] = {};
  float m_run = -3.0e38f, l_run = 0.f;

  stageKV(0, 0);
  for (int kt = 0; kt < nt; ++kt) {
    const int cur = kt & 1;
    const int k0 = kt * 64;
    asm volatile("s_waitcnt vmcnt(0)" ::: "memory");
    __builtin_amdgcn_s_barrier();
    __builtin_amdgcn_sched_barrier(0);
    if (kt + 1 < nt) stageKV(cur ^ 1, (kt + 1) * 64);

    {
      f32x16 sacc[2] = {};
      __builtin_amdgcn_s_setprio(1);
#pragma unroll
      for (int kb = 0; kb < 2; ++kb) {
#pragma unroll
        for (int dc = 0; dc < 4; ++dc) {
          int r = kb * 32 + l31;
          int g = dc * 2 + h;
          s16x8 kf = *(const s16x8*)&Kbuf[cur][r * 64 + ((g ^ SWZ(r)) * 8)];
          sacc[kb] = MFMA32(kf, qf[dc], sacc[kb]);
        }
      }
      __builtin_amdgcn_s_setprio(0);

      if (k0 + 63 > qminw) {
#pragma unroll
        for (int kb = 0; kb < 2; ++kb)
#pragma unroll
          for (int r = 0; r < 16; ++r) {
            int k_abs = k0 + kb * 32 + (r & 3) + 8 * (r >> 2) + 4 * h;
            if (k_abs > q_abs) sacc[kb][r] = -3.0e38f;
          }
      }

      float p0 = fmaxf(sacc[0][0], sacc[1][0]);
      float p1 = fmaxf(sacc[0][1], sacc[1][1]);
      float p2 = fmaxf(sacc[0][2], sacc[1][2]);
      float p3 = fmaxf(sacc[0][3], sacc[1][3]);
#pragma unroll
      for (int r = 4; r < 16; r += 4) {
        p0 = fmaxf(p0, fmaxf(sacc[0][r + 0], sacc[1][r + 0]));
        p1 = fmaxf(p1, fmaxf(sacc[0][r + 1], sacc[1][r + 1]));
        p2 = fmaxf(p2, fmaxf(sacc[0][r + 2], sacc[1][r + 2]));
        p3 = fmaxf(p3, fmaxf(sacc[0][r + 3], sacc[1][r + 3]));
      }
      float mx = fmaxf(fmaxf(p0, p1), fmaxf(p2, p3));
      mx = fmaxf(mx, __shfl_xor(mx, 32));

      if (!__all(mx <= m_run)) {
        float mnew = fmaxf(m_run, mx);
        float facv = EXP2R(m_run - mnew);
        m_run = mnew;
        l_run *= facv;
#pragma unroll
        for (int db = 0; db < 2; ++db)
#pragma unroll
          for (int r = 0; r < 16; ++r) accT[db][r] *= facv;
      }

      float s0 = 0.f, s1 = 0.f, s2 = 0.f, s3 = 0.f;
#pragma unroll
      for (int kb = 0; kb < 2; ++kb)
#pragma unroll
        for (int r = 0; r < 16; r += 4) {
          float e0 = EXP2R(sacc[kb][r + 0] - m_run);
          float e1 = EXP2R(sacc[kb][r + 1] - m_run);
          float e2 = EXP2R(sacc[kb][r + 2] - m_run);
          float e3 = EXP2R(sacc[kb][r + 3] - m_run);
          sacc[kb][r + 0] = e0; sacc[kb][r + 1] = e1;
          sacc[kb][r + 2] = e2; sacc[kb][r + 3] = e3;
          s0 += e0; s1 += e1; s2 += e2; s3 += e3;
        }
      float sum = (s0 + s1) + (s2 + s3);
      sum += __shfl_xor(sum, 32);
      l_run += sum;

      unsigned Hv[8][2];
#pragma unroll
      for (int kb = 0; kb < 2; ++kb)
#pragma unroll
        for (int q4 = 0; q4 < 4; ++q4) {
          Hv[kb * 4 + q4][0] = cvt_pk_bf16(sacc[kb][q4 * 4 + 0], sacc[kb][q4 * 4 + 1]);
          Hv[kb * 4 + q4][1] = cvt_pk_bf16(sacc[kb][q4 * 4 + 2], sacc[kb][q4 * 4 + 3]);
        }

      __builtin_amdgcn_s_setprio(1);
#pragma unroll
      for (int db = 0; db < 2; ++db) {
        int r = db * 32 + l31;
        const char* rowp = (const char*)&Vbuf[cur][r * 64];
#pragma unroll
        for (int kc = 0; kc < 4; ++kc) {
          u32x2 vlo = *(const u32x2*)(rowp + (((2 * kc) ^ SWZ(r)) * 16) + 8 * h);
          u32x2 vhi = *(const u32x2*)(rowp + (((2 * kc + 1) ^ SWZ(r)) * 16) + 8 * h);
          u32x4 vv;
          vv[0] = vlo[0]; vv[1] = vlo[1]; vv[2] = vhi[0]; vv[3] = vhi[1];
          u32x4 pv;
          pv[0] = Hv[2 * kc][0]; pv[1] = Hv[2 * kc][1];
          pv[2] = Hv[2 * kc + 1][0]; pv[3] = Hv[2 * kc + 1][1];
          accT[db] = MFMA32(__builtin_bit_cast(s16x8, vv),
                            __builtin_bit_cast(s16x8, pv), accT[db]);
        }
      }
      __builtin_amdgcn_s_setprio(0);
    }
  }

  float linv = 1.f / l_run;
#pragma unroll
  for (int db = 0; db < 2; ++db)
#pragma unroll
    for (int q4 = 0; q4 < 4; ++q4) {
      u32x2 pk;
      pk[0] = cvt_pk_bf16(accT[db][q4 * 4 + 0] * linv, accT[db][q4 * 4 + 1] * linv);
      pk[1] = cvt_pk_bf16(accT[db][q4 * 4 + 2] * linv, accT[db][q4 * 4 + 3] * linv);
      int d0 = db * 32 + 8 * q4 + 4 * h;
      *(u32x2*)&Obf[((size_t)(b * SLEN + q_abs)) * DMODEL + hd * 64 + d0] = pk;
    }
}

extern "C" void kernel_launch(void* const* d_in, const int* in_sizes, int n_in,
                              void* d_out, int out_size, void* d_ws, size_t ws_size,
                              hipStream_t stream) {
  const float* x  = (const float*)d_in[0];
  const float* Wq = (const float*)d_in[1];
  const float* Wk = (const float*)d_in[2];
  const float* Wv = (const float*)d_in[3];
  const float* Wo = (const float*)d_in[4];
  const int* pos  = (const int*)d_in[5];
  float* out = (float*)d_out;

  char* ws = (char*)d_ws;
  size_t off = 0;
  auto take = [&](size_t bytes) {
    char* p = ws + off;
    off += (bytes + 255) & ~(size_t)255;
    return p;
  };
  unsigned short* xbf  = (unsigned short*)take((size_t)MTOT * DMODEL * 2);
  unsigned short* wqkv = (unsigned short*)take((size_t)3 * DMODEL * DMODEL * 2);
  unsigned short* wobf = (unsigned short*)take((size_t)DMODEL * DMODEL * 2);
  unsigned short* Qs   = (unsigned short*)take((size_t)64 * SLEN * 64 * 2);
  unsigned short* Ks   = (unsigned short*)take((size_t)64 * SLEN * 64 * 2);
  unsigned short* Vt   = (unsigned short*)take((size_t)64 * 64 * SLEN * 2);
  unsigned short* Obf  = (unsigned short*)take((size_t)MTOT * DMODEL * 2);
  float* ctab = (float*)take((size_t)SLEN * 32 * 4);
  float* stab = (float*)take((size_t)SLEN * 32 * 4);

  // one fused prep dispatch: x-cvt (4096 blk) + W-cvt (2048) + rope (256)
  prep<<<6400, 256, 0, stream>>>(x, Wq, Wk, Wv, Wo, pos,
                                 xbf, wqkv, wobf, ctab, stab);

  // fused QKV projection, 256x128 tiles, 512 threads
  gemm_qkv<<<dim3(24, 32), 512, 0, stream>>>(xbf, wqkv, Qs, Ks, Vt,
                                             ctab, stab, 0.18033688011112042f);

  flash_attn<<<1024, 256, 0, stream>>>(Qs, Ks, Vt, Obf);

  // final projection, fp32 output
  gemm_wo<<<dim3(8, 64), 256, 0, stream>>>(Obf, wobf, out);
}

// Round 20
// 168.705 us; speedup vs baseline: 1.1377x; 1.0220x over previous
//
#include <hip/hip_runtime.h>
#include <stdint.h>

#define SLEN 2048
#define DMODEL 1024
#define NHEADS 16
#define MTOT 8192   // 4 * 2048

typedef short s16x8 __attribute__((ext_vector_type(8)));
typedef short s16x4 __attribute__((ext_vector_type(4)));
typedef float f32x4 __attribute__((ext_vector_type(4)));
typedef float f32x16 __attribute__((ext_vector_type(16)));
typedef unsigned u32x2 __attribute__((ext_vector_type(2)));
typedef unsigned u32x4 __attribute__((ext_vector_type(4)));

static __device__ __forceinline__ unsigned short f2bf(float f) {
  unsigned u = __builtin_bit_cast(unsigned, f);
  u += 0x7fffu + ((u >> 16) & 1u);           // RNE
  return (unsigned short)(u >> 16);
}

static __device__ __forceinline__ unsigned cvt_pk_bf16(float lo, float hi) {
  unsigned r;
  asm("v_cvt_pk_bf16_f32 %0, %1, %2" : "=v"(r) : "v"(lo), "v"(hi));
  return r;
}

static __device__ __forceinline__ void gload_lds16(const void* g, void* l) {
  __builtin_amdgcn_global_load_lds((__attribute__((address_space(1))) void*)g,
                                   (__attribute__((address_space(3))) void*)l,
                                   16, 0, 0);
}

// raw v_exp_f32 (libm exp2f adds range fixups; args <=8 finite or -3e38)
#define EXP2R(x) __builtin_amdgcn_exp2f(x)

#define MFMA16(a, b, c) __builtin_amdgcn_mfma_f32_16x16x32_bf16(a, b, c, 0, 0, 0)
#define MFMA32(a, b, c) __builtin_amdgcn_mfma_f32_32x32x16_bf16(a, b, c, 0, 0, 0)
// full-rank row swizzle: rows r, r+8, r+16, ... get distinct granule perms
#define SWZ(r) ((((r) & 7) ^ (((r) >> 3) & 7)))

// ------------- fused prep: x->bf16, W->bf16, RoPE tables (one dispatch) -----
__global__ void __launch_bounds__(256) prep(const float* __restrict__ x,
                                            const float* __restrict__ Wq,
                                            const float* __restrict__ Wk,
                                            const float* __restrict__ Wv,
                                            const float* __restrict__ Wo,
                                            const int* __restrict__ pos,
                                            unsigned short* __restrict__ xbf,
                                            unsigned short* __restrict__ wqkv,
                                            unsigned short* __restrict__ wobf,
                                            float* __restrict__ ctab,
                                            float* __restrict__ stab) {
  int blk = blockIdx.x;
  if (blk < 4096) {                           // x: 8M floats, 8/thread
    int i = blk * 256 + threadIdx.x;
    f32x4 a = ((const f32x4*)x)[i * 2];
    f32x4 b = ((const f32x4*)x)[i * 2 + 1];
    s16x8 o;
#pragma unroll
    for (int j = 0; j < 4; ++j) o[j] = (short)f2bf(a[j]);
#pragma unroll
    for (int j = 0; j < 4; ++j) o[4 + j] = (short)f2bf(b[j]);
    ((s16x8*)xbf)[i] = o;
  } else if (blk < 6144) {                    // weights: 4 x 1M floats
    int wsel = (blk - 4096) >> 9;             // 512 blocks per matrix
    const float* src = wsel == 0 ? Wq : wsel == 1 ? Wk : wsel == 2 ? Wv : Wo;
    unsigned short* dst = (wsel < 3) ? (wqkv + (size_t)wsel * DMODEL * DMODEL) : wobf;
    int i = ((blk - 4096) & 511) * 256 + threadIdx.x;
    f32x4 a = ((const f32x4*)src)[i * 2];
    f32x4 b = ((const f32x4*)src)[i * 2 + 1];
    s16x8 o;
#pragma unroll
    for (int j = 0; j < 4; ++j) o[j] = (short)f2bf(a[j]);
#pragma unroll
    for (int j = 0; j < 4; ++j) o[4 + j] = (short)f2bf(b[j]);
    ((s16x8*)dst)[i] = o;
  } else {                                    // rope tables: 65536 entries
    int g = (blk - 6144) * 256 + threadIdx.x;
    int s = g >> 5, i = g & 31;
    float p = (float)pos[s];
    float ang = p * exp2f(-(float)i * 0.41524101186092029f);
    ctab[g] = cosf(ang);
    stab[g] = sinf(ang);
  }
}

// ---------------- QKV GEMM: C[8192][3072] = x * W_qkv^T, 128x128 tile -------
// (R18's proven structure: 256 thr, 3-buffer 2-deep counted-vmcnt single
// barrier, 3 blocks/CU; R19's 256x128 was slightly worse — reverted.)
// XCD mapping: per-XCD working set <= A 2MB + B 2MB = 4MB L2 (n in 3 groups).
// Epilogue per 128-col block: n0>>10 = 0 -> Q (RoPE+scale), 1 -> K, 2 -> V^T.
__global__ void __launch_bounds__(256) gemm_qkv(const unsigned short* __restrict__ A,
                                                const unsigned short* __restrict__ B,
                                                unsigned short* __restrict__ dstQ,
                                                unsigned short* __restrict__ dstK,
                                                unsigned short* __restrict__ dstV,
                                                const float* __restrict__ ctab,
                                                const float* __restrict__ stab,
                                                float scale) {
  __shared__ unsigned short ldsA[3][128 * 32];
  __shared__ unsigned short ldsB[3][128 * 32];
  const int tid = threadIdx.x;
  const int lane = tid & 63;
  const int wave = tid >> 6;
  const int wm = wave >> 1, wn = wave & 1;

  int flat = blockIdx.y * 24 + blockIdx.x;    // 1536 blocks
  int xcd = flat & 7, idx = flat >> 3;        // idx 0..191 (per-XCD issue order)
  int g = idx >> 6;                           // n-group 0..2 (8 n-blocks each)
  int local = idx & 63;
  int lm = local >> 3, ln = local & 7;
  const int m0 = (xcd * 8 + lm) * 128;
  const int n0 = (g * 8 + ln) * 128;
  const int l15 = lane & 15, lhi = lane >> 4;

  f32x4 acc[4][4] = {};

  auto stage = [&](int buf, int kt) {
    const int kbase = kt * 32;
#pragma unroll
    for (int issue = 0; issue < 2; ++issue) {
      int c = issue * 256 + wave * 64 + lane;   // chunk id 0..511
      int row = c >> 2, kc = c & 3;
      int kcg = kc ^ ((row >> 1) & 3);          // source chunk for this slot
      gload_lds16(A + (size_t)(m0 + row) * 1024 + kbase + kcg * 8,
                  &ldsA[buf][(issue * 256 + wave * 64) * 8]);
      gload_lds16(B + (size_t)(n0 + row) * 1024 + kbase + kcg * 8,
                  &ldsB[buf][(issue * 256 + wave * 64) * 8]);
    }
  };

  stage(0, 0);
  stage(1, 1);
  for (int kt = 0; kt < 32; ++kt) {
    if (kt + 1 < 32) {
      asm volatile("s_waitcnt vmcnt(4)" ::: "memory");
    } else {
      asm volatile("s_waitcnt vmcnt(0)" ::: "memory");
    }
    __builtin_amdgcn_s_barrier();
    __builtin_amdgcn_sched_barrier(0);
    if (kt + 2 < 32) stage((kt + 2) % 3, kt + 2);

    const int buf = kt % 3;
    s16x8 af[4], bf[4];
#pragma unroll
    for (int mi = 0; mi < 4; ++mi) {
      int row = wm * 64 + mi * 16 + l15;
      int kc = lhi ^ ((row >> 1) & 3);
      af[mi] = *(const s16x8*)&ldsA[buf][row * 32 + kc * 8];
    }
#pragma unroll
    for (int ni = 0; ni < 4; ++ni) {
      int row = wn * 64 + ni * 16 + l15;
      int kc = lhi ^ ((row >> 1) & 3);
      bf[ni] = *(const s16x8*)&ldsB[buf][row * 32 + kc * 8];
    }
#pragma unroll
    for (int mi = 0; mi < 4; ++mi)
#pragma unroll
      for (int ni = 0; ni < 4; ++ni)
        acc[mi][ni] = MFMA16(af[mi], bf[ni], acc[mi][ni]);
  }

  // epilogue: C layout col = lane&15, row = (lane>>4)*4 + i
  const int which = n0 >> 10;                 // 0=Q 1=K 2=V (uniform per block)
  if (which < 2) {
    unsigned short* dst = (which == 0) ? dstQ : dstK;
    const float sc = (which == 0) ? scale : 1.0f;
#pragma unroll
    for (int mi = 0; mi < 4; ++mi)
#pragma unroll
      for (int ni = 0; ni < 4; ++ni)
#pragma unroll
        for (int i = 0; i < 4; ++i) {
          int r = m0 + wm * 64 + mi * 16 + lhi * 4 + i;
          int nn = (n0 & 1023) + wn * 64 + ni * 16 + l15;
          float v = acc[mi][ni][i];
          float p = __shfl_xor(v, 1);           // RoPE partner
          int s = r & (SLEN - 1);
          int d = nn & 63;
          int fi = d >> 1;
          float c = ctab[s * 32 + fi], sn = stab[s * 32 + fi];
          float o = (d & 1) ? (p * sn + v * c) : (v * c - p * sn);
          o *= sc;
          int b = r >> 11, h = nn >> 6;
          dst[((size_t)(b * NHEADS + h) * SLEN + s) * 64 + d] = f2bf(o);
        }
  } else {  // V^T [bh][d][s]
#pragma unroll
    for (int mi = 0; mi < 4; ++mi)
#pragma unroll
      for (int ni = 0; ni < 4; ++ni) {
        int r0 = m0 + wm * 64 + mi * 16 + lhi * 4;
        int nn = (n0 & 1023) + wn * 64 + ni * 16 + l15;
        int b = r0 >> 11, s0 = r0 & (SLEN - 1);
        int h = nn >> 6, d = nn & 63;
        s16x4 pk;
#pragma unroll
        for (int i = 0; i < 4; ++i) pk[i] = (short)f2bf(acc[mi][ni][i]);
        *(s16x4*)&dstV[((size_t)(b * NHEADS + h) * 64 + d) * SLEN + s0] = pk;
      }
  }
}

// ---------------- Wo GEMM: out[8192][1024] = Obf * Wo^T (fp32 out) ----------
__global__ void __launch_bounds__(256) gemm_wo(const unsigned short* __restrict__ A,
                                               const unsigned short* __restrict__ B,
                                               float* __restrict__ dst) {
  __shared__ unsigned short ldsA[3][128 * 32];
  __shared__ unsigned short ldsB[3][128 * 32];
  const int tid = threadIdx.x;
  const int lane = tid & 63;
  const int wave = tid >> 6;
  const int wm = wave >> 1, wn = wave & 1;

  int flat = blockIdx.y * 8 + blockIdx.x;     // 512 blocks
  int logical = (flat & 7) * 64 + (flat >> 3);
  const int m0 = (logical >> 3) * 128;
  const int n0 = (logical & 7) * 128;
  const int l15 = lane & 15, lhi = lane >> 4;

  f32x4 acc[4][4] = {};

  auto stage = [&](int buf, int kt) {
    const int kbase = kt * 32;
#pragma unroll
    for (int issue = 0; issue < 2; ++issue) {
      int c = issue * 256 + wave * 64 + lane;
      int row = c >> 2, kc = c & 3;
      int kcg = kc ^ ((row >> 1) & 3);
      gload_lds16(A + (size_t)(m0 + row) * 1024 + kbase + kcg * 8,
                  &ldsA[buf][(issue * 256 + wave * 64) * 8]);
      gload_lds16(B + (size_t)(n0 + row) * 1024 + kbase + kcg * 8,
                  &ldsB[buf][(issue * 256 + wave * 64) * 8]);
    }
  };

  stage(0, 0);
  stage(1, 1);
  for (int kt = 0; kt < 32; ++kt) {
    if (kt + 1 < 32) {
      asm volatile("s_waitcnt vmcnt(4)" ::: "memory");
    } else {
      asm volatile("s_waitcnt vmcnt(0)" ::: "memory");
    }
    __builtin_amdgcn_s_barrier();
    __builtin_amdgcn_sched_barrier(0);
    if (kt + 2 < 32) stage((kt + 2) % 3, kt + 2);

    const int buf = kt % 3;
    s16x8 af[4], bf[4];
#pragma unroll
    for (int mi = 0; mi < 4; ++mi) {
      int row = wm * 64 + mi * 16 + l15;
      int kc = lhi ^ ((row >> 1) & 3);
      af[mi] = *(const s16x8*)&ldsA[buf][row * 32 + kc * 8];
    }
#pragma unroll
    for (int ni = 0; ni < 4; ++ni) {
      int row = wn * 64 + ni * 16 + l15;
      int kc = lhi ^ ((row >> 1) & 3);
      bf[ni] = *(const s16x8*)&ldsB[buf][row * 32 + kc * 8];
    }
#pragma unroll
    for (int mi = 0; mi < 4; ++mi)
#pragma unroll
      for (int ni = 0; ni < 4; ++ni)
        acc[mi][ni] = MFMA16(af[mi], bf[ni], acc[mi][ni]);
  }

#pragma unroll
  for (int mi = 0; mi < 4; ++mi)
#pragma unroll
    for (int ni = 0; ni < 4; ++ni)
#pragma unroll
      for (int i = 0; i < 4; ++i) {
        int r = m0 + wm * 64 + mi * 16 + lhi * 4 + i;
        int n = n0 + wn * 64 + ni * 16 + l15;
        dst[(size_t)r * 1024 + n] = acc[mi][ni][i];
      }
}

// ---------------- causal flash attention, v17: + THR=8 defer-max (T13) ------
// v16 (R18, passing) + threshold defer: skip the accT rescale while the tile
// max grows by <= 8 (exp2 domain) — P bounded by 2^8=256, safe in f32 accum
// and bf16 pack. Wave-level __all previously rescaled on MOST tiles (any of
// 32 rows growing); growth is almost always tiny -> ~35 serial VALU ops/tile
// saved on the softmax critical path (flash is VALU-bound, VALUBusy 59%).
__global__ void __launch_bounds__(256, 4) flash_attn(const unsigned short* __restrict__ Q,
                                                     const unsigned short* __restrict__ K,
                                                     const unsigned short* __restrict__ Vt,
                                                     unsigned short* __restrict__ Obf) {
  __shared__ unsigned short Kbuf[2][64 * 64];   // 8 KB each
  __shared__ unsigned short Vbuf[2][64 * 64];   // rows = d, cols = k-local

  const int tid = threadIdx.x, lane = tid & 63, w = tid >> 6;
  const int l31 = lane & 31, h = lane >> 5;     // h: which 32-lane half

  // XCD round-robin extraction + Graeco-Latin balanced (bh, t)
  int id = blockIdx.x;                          // 0..1023
  int xcd = id & 7, idx = id >> 3;              // idx 0..127 per XCD
  const int s_ = idx & 3;
  const int bhl = (idx >> 2) & 7;
  const int g_ = idx >> 5;
  const int mul2g = (g_ == 0) ? 0 : (g_ == 1) ? 2 : (g_ == 2) ? 3 : 1;
  const int t = 4 * (s_ ^ g_) + (s_ ^ mul2g);   // 0..15, balanced both ways
  const int bh = xcd * 8 + bhl;
  const int b = bh >> 4, hd = bh & 15;

  const unsigned short* Qb = Q + (size_t)bh * SLEN * 64;
  const unsigned short* Kb = K + (size_t)bh * SLEN * 64;
  const unsigned short* Vb = Vt + (size_t)bh * 64 * SLEN;

  const int qbase = t * 128;
  const int nt = 2 * t + 2;                     // k-tiles incl. diagonal
  const int q_abs = qbase + w * 32 + l31;
  const int qminw = qbase + w * 32;

  auto stageKV = [&](int buf, int k0) {
#pragma unroll
    for (int i = 0; i < 2; ++i) {
      int c = i * 256 + tid;                    // 16B chunk 0..511
      int row = c >> 3, cg = c & 7;
      int col = ((cg ^ SWZ(row)) * 8);
      gload_lds16(Kb + (size_t)(k0 + row) * 64 + col, &Kbuf[buf][c * 8]);
      gload_lds16(Vb + (size_t)row * SLEN + k0 + col, &Vbuf[buf][c * 8]);
    }
  };

  s16x8 qf[4];
#pragma unroll
  for (int dc = 0; dc < 4; ++dc)
    qf[dc] = *(const s16x8*)&Qb[(size_t)q_abs * 64 + dc * 16 + h * 8];

  f32x16 accT[2] = {};
  float m_run = -3.0e38f, l_run = 0.f;

  stageKV(0, 0);
  for (int kt = 0; kt < nt; ++kt) {
    const int cur = kt & 1;
    const int k0 = kt * 64;
    asm volatile("s_waitcnt vmcnt(0)" ::: "memory");
    __builtin_amdgcn_s_barrier();
    __builtin_amdgcn_sched_barrier(0);
    if (kt + 1 < nt) stageKV(cur ^ 1, (kt + 1) * 64);

    {
      f32x16 sacc[2] = {};
      __builtin_amdgcn_s_setprio(1);
#pragma unroll
      for (int kb = 0; kb < 2; ++kb) {
#pragma unroll
        for (int dc = 0; dc < 4; ++dc) {
          int r = kb * 32 + l31;
          int g = dc * 2 + h;
          s16x8 kf = *(const s16x8*)&Kbuf[cur][r * 64 + ((g ^ SWZ(r)) * 8)];
          sacc[kb] = MFMA32(kf, qf[dc], sacc[kb]);
        }
      }
      __builtin_amdgcn_s_setprio(0);

      if (k0 + 63 > qminw) {
#pragma unroll
        for (int kb = 0; kb < 2; ++kb)
#pragma unroll
          for (int r = 0; r < 16; ++r) {
            int k_abs = k0 + kb * 32 + (r & 3) + 8 * (r >> 2) + 4 * h;
            if (k_abs > q_abs) sacc[kb][r] = -3.0e38f;
          }
      }

      float p0 = fmaxf(sacc[0][0], sacc[1][0]);
      float p1 = fmaxf(sacc[0][1], sacc[1][1]);
      float p2 = fmaxf(sacc[0][2], sacc[1][2]);
      float p3 = fmaxf(sacc[0][3], sacc[1][3]);
#pragma unroll
      for (int r = 4; r < 16; r += 4) {
        p0 = fmaxf(p0, fmaxf(sacc[0][r + 0], sacc[1][r + 0]));
        p1 = fmaxf(p1, fmaxf(sacc[0][r + 1], sacc[1][r + 1]));
        p2 = fmaxf(p2, fmaxf(sacc[0][r + 2], sacc[1][r + 2]));
        p3 = fmaxf(p3, fmaxf(sacc[0][r + 3], sacc[1][r + 3]));
      }
      float mx = fmaxf(fmaxf(p0, p1), fmaxf(p2, p3));
      mx = fmaxf(mx, __shfl_xor(mx, 32));

      // T13 defer-max: rescale only when the max grows by > 8 (exp2 domain);
      // otherwise keep m_run and let P range up to 2^8.
      if (!__all(mx - m_run <= 8.0f)) {
        float mnew = fmaxf(m_run, mx);
        float facv = EXP2R(m_run - mnew);
        m_run = mnew;
        l_run *= facv;
#pragma unroll
        for (int db = 0; db < 2; ++db)
#pragma unroll
          for (int r = 0; r < 16; ++r) accT[db][r] *= facv;
      }

      float s0 = 0.f, s1 = 0.f, s2 = 0.f, s3 = 0.f;
#pragma unroll
      for (int kb = 0; kb < 2; ++kb)
#pragma unroll
        for (int r = 0; r < 16; r += 4) {
          float e0 = EXP2R(sacc[kb][r + 0] - m_run);
          float e1 = EXP2R(sacc[kb][r + 1] - m_run);
          float e2 = EXP2R(sacc[kb][r + 2] - m_run);
          float e3 = EXP2R(sacc[kb][r + 3] - m_run);
          sacc[kb][r + 0] = e0; sacc[kb][r + 1] = e1;
          sacc[kb][r + 2] = e2; sacc[kb][r + 3] = e3;
          s0 += e0; s1 += e1; s2 += e2; s3 += e3;
        }
      float sum = (s0 + s1) + (s2 + s3);
      sum += __shfl_xor(sum, 32);
      l_run += sum;

      unsigned Hv[8][2];
#pragma unroll
      for (int kb = 0; kb < 2; ++kb)
#pragma unroll
        for (int q4 = 0; q4 < 4; ++q4) {
          Hv[kb * 4 + q4][0] = cvt_pk_bf16(sacc[kb][q4 * 4 + 0], sacc[kb][q4 * 4 + 1]);
          Hv[kb * 4 + q4][1] = cvt_pk_bf16(sacc[kb][q4 * 4 + 2], sacc[kb][q4 * 4 + 3]);
        }

      __builtin_amdgcn_s_setprio(1);
#pragma unroll
      for (int db = 0; db < 2; ++db) {
        int r = db * 32 + l31;
        const char* rowp = (const char*)&Vbuf[cur][r * 64];
#pragma unroll
        for (int kc = 0; kc < 4; ++kc) {
          u32x2 vlo = *(const u32x2*)(rowp + (((2 * kc) ^ SWZ(r)) * 16) + 8 * h);
          u32x2 vhi = *(const u32x2*)(rowp + (((2 * kc + 1) ^ SWZ(r)) * 16) + 8 * h);
          u32x4 vv;
          vv[0] = vlo[0]; vv[1] = vlo[1]; vv[2] = vhi[0]; vv[3] = vhi[1];
          u32x4 pv;
          pv[0] = Hv[2 * kc][0]; pv[1] = Hv[2 * kc][1];
          pv[2] = Hv[2 * kc + 1][0]; pv[3] = Hv[2 * kc + 1][1];
          accT[db] = MFMA32(__builtin_bit_cast(s16x8, vv),
                            __builtin_bit_cast(s16x8, pv), accT[db]);
        }
      }
      __builtin_amdgcn_s_setprio(0);
    }
  }

  float linv = 1.f / l_run;
#pragma unroll
  for (int db = 0; db < 2; ++db)
#pragma unroll
    for (int q4 = 0; q4 < 4; ++q4) {
      u32x2 pk;
      pk[0] = cvt_pk_bf16(accT[db][q4 * 4 + 0] * linv, accT[db][q4 * 4 + 1] * linv);
      pk[1] = cvt_pk_bf16(accT[db][q4 * 4 + 2] * linv, accT[db][q4 * 4 + 3] * linv);
      int d0 = db * 32 + 8 * q4 + 4 * h;
      *(u32x2*)&Obf[((size_t)(b * SLEN + q_abs)) * DMODEL + hd * 64 + d0] = pk;
    }
}

extern "C" void kernel_launch(void* const* d_in, const int* in_sizes, int n_in,
                              void* d_out, int out_size, void* d_ws, size_t ws_size,
                              hipStream_t stream) {
  const float* x  = (const float*)d_in[0];
  const float* Wq = (const float*)d_in[1];
  const float* Wk = (const float*)d_in[2];
  const float* Wv = (const float*)d_in[3];
  const float* Wo = (const float*)d_in[4];
  const int* pos  = (const int*)d_in[5];
  float* out = (float*)d_out;

  char* ws = (char*)d_ws;
  size_t off = 0;
  auto take = [&](size_t bytes) {
    char* p = ws + off;
    off += (bytes + 255) & ~(size_t)255;
    return p;
  };
  unsigned short* xbf  = (unsigned short*)take((size_t)MTOT * DMODEL * 2);
  unsigned short* wqkv = (unsigned short*)take((size_t)3 * DMODEL * DMODEL * 2);
  unsigned short* wobf = (unsigned short*)take((size_t)DMODEL * DMODEL * 2);
  unsigned short* Qs   = (unsigned short*)take((size_t)64 * SLEN * 64 * 2);
  unsigned short* Ks   = (unsigned short*)take((size_t)64 * SLEN * 64 * 2);
  unsigned short* Vt   = (unsigned short*)take((size_t)64 * 64 * SLEN * 2);
  unsigned short* Obf  = (unsigned short*)take((size_t)MTOT * DMODEL * 2);
  float* ctab = (float*)take((size_t)SLEN * 32 * 4);
  float* stab = (float*)take((size_t)SLEN * 32 * 4);

  // one fused prep dispatch: x-cvt (4096 blk) + W-cvt (2048) + rope (256)
  prep<<<6400, 256, 0, stream>>>(x, Wq, Wk, Wv, Wo, pos,
                                 xbf, wqkv, wobf, ctab, stab);

  // fused QKV projection, 128x128 tiles (R18 structure)
  gemm_qkv<<<dim3(24, 64), 256, 0, stream>>>(xbf, wqkv, Qs, Ks, Vt,
                                             ctab, stab, 0.18033688011112042f);

  flash_attn<<<1024, 256, 0, stream>>>(Qs, Ks, Vt, Obf);

  // final projection, fp32 output
  gemm_wo<<<dim3(8, 64), 256, 0, stream>>>(Obf, wobf, out);
}